// Round 12
// baseline (347.823 us; speedup 1.0000x reference)
//
#include <hip/hip_runtime.h>
#include <stdint.h>

typedef short  bf16x8 __attribute__((ext_vector_type(8)));
typedef float  f32x4  __attribute__((ext_vector_type(4)));

// ---------------- common helpers ----------------

__device__ __forceinline__ short f2bf(float f) {
    uint32_t u = __builtin_bit_cast(uint32_t, f);
    u += 0x7FFFu + ((u >> 16) & 1u);          // RNE to bf16
    return (short)(u >> 16);
}

// u[g][s] = COMP[INV[g]][s] for p4m (verified by rounds 1-11 passing)
__device__ __forceinline__ int u_index(int g, int s) {
    int r  = g & 3, m  = g >> 2;
    int r2 = s & 3, ms = s >> 2;
    if (!m) { int rr = (r2 - r) & 3; return ms ? (4 + rr) : rr; }
    else    { int rr = (r - r2) & 3; return ms ? rr : (4 + rr); }
}

// async global->LDS, 16B per lane (LDS dest wave-uniform, HW adds lane*16)
__device__ __forceinline__ void gload_lds16(const void* g, void* l) {
    __builtin_amdgcn_global_load_lds(
        (const __attribute__((address_space(1))) uint32_t*)g,
        (__attribute__((address_space(3))) uint32_t*)l, 16, 0, 0);
}

// ---------------- workspace layout ----------------
// xb  : bf16 [16][66][66][512]          zero-padded NHWC input
// bank: bf16 [kc 16][t 9][kg 4][oc 512][8]  transformed weights,
//       fragment-ordered; weights are read global->register (L1/L2-served)
#define XB_BYTES  (16LL * 66 * 66 * 512 * 2)
#define BK_BYTES  (16LL * 9 * 4 * 512 * 8 * 2)
#define WS_NEEDED (XB_BYTES + BK_BYTES)

// ---------------- prep kernels ----------------

// Coalesced NCHW fp32 -> padded NHWC bf16, via LDS transpose.
__global__ __launch_bounds__(256) void prep_x2(const float* __restrict__ x,
                                               short* __restrict__ xb) {
    __shared__ float t[64][65];
    const int h = blockIdx.x, kc8 = blockIdx.y, b = blockIdx.z;
    const int k0 = kc8 * 64;
    const int tid = threadIdx.x;
    const int w  = tid & 63, kq = tid >> 6;
    const float* xp = x + ((size_t)(b * 512 + k0 + kq) * 4096) + h * 64 + w;
    #pragma unroll
    for (int i = 0; i < 16; ++i)
        t[kq + 4 * i][w] = xp[(size_t)(4 * i) * 4096];
    __syncthreads();
    const int w2 = tid >> 3, kk = tid & 7;
    #pragma unroll
    for (int half = 0; half < 2; ++half) {
        const int ww = w2 + 32 * half;
        bf16x8 v;
        #pragma unroll
        for (int j = 0; j < 8; ++j) v[j] = f2bf(t[kk * 8 + j][ww]);
        size_t o = (((size_t)b * 66 + h + 1) * 66 + (ww + 1)) * 512 + k0 + kk * 8;
        *reinterpret_cast<bf16x8*>(&xb[o]) = v;
    }
}

// zero the 1-px border of the padded NHWC buffer
__global__ __launch_bounds__(256) void zero_border(short* __restrict__ xb) {
    int idx = blockIdx.x * 256 + threadIdx.x;      // 16*260*64 = 266240
    if (idx >= 16 * 260 * 64) return;
    int kg = idx & 63;
    int rest = idx >> 6;
    int b  = rest / 260;
    int pe = rest - b * 260;
    int hh, ww;
    if      (pe < 66)  { hh = 0;            ww = pe; }
    else if (pe < 132) { hh = 65;           ww = pe - 66; }
    else if (pe < 196) { hh = pe - 132 + 1; ww = 0; }
    else               { hh = pe - 196 + 1; ww = 65; }
    size_t o = (((size_t)b * 66 + hh) * 66 + ww) * 512 + kg * 8;
    bf16x8 z = {0,0,0,0,0,0,0,0};
    *reinterpret_cast<bf16x8*>(&xb[o]) = z;
}

// wrel fp32 [64][64][8][3][3] -> bank bf16 [kc][t][kg][oc][8]
__global__ __launch_bounds__(256) void prep_w(const float* __restrict__ wrel,
                                              short* __restrict__ bank) {
    int tg = blockIdx.x * 256 + threadIdx.x;    // 9*16*4*512 = 294912
    int oc = tg & 511;
    int kg = (tg >> 9) & 3;
    int kc = (tg >> 11) & 15;
    int t  = tg >> 15;                          // 0..8
    int ki = t / 3, kj = t - ki * 3;
    int g = oc & 7, co = oc >> 3;
    int r = g & 3, m = g >> 2;
    int a0, b0;
    switch (r) {
        case 0:  a0 = ki;     b0 = kj;     break;
        case 1:  a0 = kj;     b0 = 2 - ki; break;
        case 2:  a0 = 2 - ki; b0 = 2 - kj; break;
        default: a0 = 2 - kj; b0 = ki;     break;
    }
    if (m) b0 = 2 - b0;
    int ci = kc * 4 + kg;
    const float* wp = wrel + (size_t)(co * 64 + ci) * 72 + a0 * 3 + b0;
    bf16x8 v;
    #pragma unroll
    for (int j = 0; j < 8; ++j) v[j] = f2bf(wp[u_index(g, j) * 9]);
    size_t o = ((((size_t)kc * 9 + t) * 4 + kg) * 512 + oc) * 8;
    *reinterpret_cast<bf16x8*>(&bank[o]) = v;
}

// ---------------- main MFMA kernel ----------------
// block: 256 threads = 4 waves, 64 oc x 256 px (16x16 tile); wave 64oc x 64px.
// Weights: global->register (L1/L2-served, no LDS, no staging barriers).
// X: LDS double-buffer via global_load_lds, ONE barrier per chunk.
// LDS 43KB -> 3 blocks/CU (12 waves) at VGPR<=~170.
#define XS_SH (21 * 512)            // 21 slots: 4kg x 336px, 16B frags

#define STAGE_X(XS, kc)                                                    \
    {                                                                      \
        _Pragma("unroll")                                                  \
        for (int q = 0; q < 6; ++q) {                                      \
            int it = wid + 4 * q;                                          \
            if (it < 21)                                                   \
                gload_lds16(xb + (size_t)xoff[q] + (kc) * 32,              \
                            &XS[it * 512]);                                \
        }                                                                  \
    }

// per chunk per wave: 3 kj x {6 B ds_reads + 3 ki x (4 A global-loads,
// 16 MFMA)}. No barriers inside: compiler overlaps A-loads of (ki+1)/(kj+1)
// with current MFMAs; lgkm/vm waits are use-driven.
#define COMPUTE_CHUNK(XS, kc)                                              \
    {                                                                      \
        _Pragma("unroll")                                                  \
        for (int kj = 0; kj < 3; ++kj) {                                   \
            bf16x8 bfr[6];                                                 \
            _Pragma("unroll")                                              \
            for (int rr = 0; rr < 6; ++rr)                                 \
                bfr[rr] = *reinterpret_cast<const bf16x8*>(                \
                    &XS[(lkg * 336 + (wid * 4 + rr) * 18 + l15 + (kj)) * 8]); \
            _Pragma("unroll")                                              \
            for (int ki = 0; ki < 3; ++ki) {                               \
                const int t = ki * 3 + kj;                                 \
                bf16x8 a[4];                                               \
                _Pragma("unroll")                                          \
                for (int mi = 0; mi < 4; ++mi)                             \
                    a[mi] = *reinterpret_cast<const bf16x8*>(              \
                        wbase + (size_t)((kc) * 9 + t) * 16384 + mi * 128); \
                _Pragma("unroll")                                          \
                for (int nj = 0; nj < 4; ++nj) {                           \
                    bf16x8 bv = bfr[nj + ki];                              \
                    _Pragma("unroll")                                      \
                    for (int mi = 0; mi < 4; ++mi)                         \
                        acc[mi][nj] = __builtin_amdgcn_mfma_f32_16x16x32_bf16( \
                            a[mi], bv, acc[mi][nj], 0, 0, 0);              \
                }                                                          \
            }                                                              \
        }                                                                  \
    }

__global__ __launch_bounds__(256, 3) void gconv_mfma(
    const short* __restrict__ xb, const short* __restrict__ bank,
    const float* __restrict__ bias, float* __restrict__ out)
{
    __shared__ __attribute__((aligned(16))) short xsA[XS_SH], xsB[XS_SH];

    const int st  = blockIdx.x;           // 16 spatial tiles (4h x 4w)
    const int ot  = blockIdx.y;           // 8 oc tiles (64 oc each)
    const int b   = blockIdx.z;           // 16 batches
    const int h0  = (st >> 2) * 16;
    const int w0  = (st & 3) * 16;
    const int oc0 = ot * 64;

    const int tid  = threadIdx.x;
    const int lane = tid & 63;
    const int wid  = tid >> 6;            // 0..3 (row quad)
    const int l15  = lane & 15;
    const int lkg  = lane >> 4;

    // per-lane weight base: frag(t,kg=lkg,mi) at
    // wbase + (kc*9+t)*16384 + mi*128   (elements)
    const short* wbase = bank + lkg * 4096 + (size_t)(oc0 + l15) * 8;

    f32x4 acc[4][4];
    #pragma unroll
    for (int i = 0; i < 4; ++i)
        #pragma unroll
        for (int j = 0; j < 4; ++j)
            #pragma unroll
            for (int e = 0; e < 4; ++e) acc[i][j][e] = 0.f;

    const int xrow_base = (b * 66 + h0) * 66 + w0;   // padded coords

    // per-thread global element offsets (32-bit ok: xb < 36M elems)
    int xoff[6];
    #pragma unroll
    for (int q = 0; q < 6; ++q) {
        int it = wid + 4 * q;
        if (it > 20) it = 20;                        // unused slot, safe addr
        int slot = it * 64 + lane;                   // < 1344
        int kg = slot / 336;                         // 0..3
        int px = slot - kg * 336;
        px = px < 324 ? px : 323;                    // pad slots -> dup
        int r = px / 18;
        int c = px - r * 18;
        xoff[q] = (xrow_base + r * 66 + c) * 512 + kg * 8;
    }

    // ---- K-loop: 16 chunks of 32 channels; x dbuf, 1 barrier per chunk ----
    STAGE_X(xsA, 0);
    __syncthreads();
    for (int kc2 = 0; kc2 < 8; ++kc2) {
        STAGE_X(xsB, 2 * kc2 + 1);
        COMPUTE_CHUNK(xsA, 2 * kc2);
        __syncthreads();                  // drains vmcnt -> xsB ready, xsA free
        if (kc2 < 7) STAGE_X(xsA, 2 * kc2 + 2);
        COMPUTE_CHUNK(xsB, 2 * kc2 + 1);
        __syncthreads();
    }

    // ---- epilogue: D row=(lane>>4)*4+reg -> oc, col=lane&15 -> pixel ----
    #pragma unroll
    for (int mi = 0; mi < 4; ++mi) {
        #pragma unroll
        for (int j = 0; j < 4; ++j) {
            const int oc_g = oc0 + mi * 16 + lkg * 4 + j;
            const float bv = bias[oc_g >> 3];
            float* op = out + ((size_t)b * 512 + oc_g) * 4096;
            #pragma unroll
            for (int nj = 0; nj < 4; ++nj) {
                const int hh = h0 + wid * 4 + nj;
                op[hh * 64 + w0 + l15] = acc[mi][nj][j] + bv;
            }
        }
    }
}

// ---------------- fp32 fallback (ws too small; verified round 1) ----------
__global__ __launch_bounds__(256) void gconv_direct(
    const float* __restrict__ x, const float* __restrict__ wrel,
    const float* __restrict__ bias, float* __restrict__ out)
{
    __shared__ float xsf[18][20];
    __shared__ float wsf[16][9];
    const int st = blockIdx.x, ct = blockIdx.y, b = blockIdx.z;
    const int h0 = (st >> 2) * 16, w0 = (st & 3) * 16, oc0 = ct * 16;
    const int tid = threadIdx.x;
    const int ch = tid & 15, blk = tid >> 4;
    const int by = (blk >> 2) * 4, bx = (blk & 3) * 4;
    const int oc = oc0 + ch, g = oc & 7, co = oc >> 3;
    const int wl_c = tid / 9, wl_k = tid - wl_c * 9;
    const int wl_i = wl_k / 3, wl_j = wl_k - wl_i * 3;
    const int wl_oc = oc0 + wl_c, wl_g = wl_oc & 7, wl_co = wl_oc >> 3;
    int a0, b0;
    { const int r = wl_g & 3, m = wl_g >> 2;
      switch (r) { case 0: a0=wl_i; b0=wl_j; break; case 1: a0=wl_j; b0=2-wl_i; break;
                   case 2: a0=2-wl_i; b0=2-wl_j; break; default: a0=2-wl_j; b0=wl_i; break; }
      if (m) b0 = 2 - b0; }
    float acc[4][4];
    #pragma unroll
    for (int i=0;i<4;++i) for (int j=0;j<4;++j) acc[i][j]=0.f;
    for (int t = 0; t < 512; ++t) {
        const int ci = t >> 3, s = t & 7;
        __syncthreads();
        const float* xp = x + (((size_t)(b * 64 + ci) * 8 + s) * 4096);
        for (int idx = tid; idx < 18 * 18; idx += 256) {
            const int rr = idx / 18, cc = idx - rr * 18;
            const int gh = h0 - 1 + rr, gw = w0 - 1 + cc;
            float v = 0.f;
            if (gh >= 0 && gh < 64 && gw >= 0 && gw < 64) v = xp[gh * 64 + gw];
            xsf[rr][cc] = v;
        }
        if (tid < 144) {
            const int u = u_index(wl_g, s);
            wsf[wl_c][wl_k] = wrel[((size_t)(wl_co*64+ci)*8+u)*9 + a0*3 + b0];
        }
        __syncthreads();
        float wr[9];
        #pragma unroll
        for (int k=0;k<9;++k) wr[k]=wsf[ch][k];
        float xv[6][6];
        #pragma unroll
        for (int i=0;i<6;++i) for (int j=0;j<6;++j) xv[i][j]=xsf[by+i][bx+j];
        #pragma unroll
        for (int py=0;py<4;++py) for (int px=0;px<4;++px)
            for (int ki=0;ki<3;++ki) for (int kj=0;kj<3;++kj)
                acc[py][px] += xv[py+ki][px+kj]*wr[ki*3+kj];
    }
    const float bv = bias[co];
    float* op = out + (((size_t)(b*64+co)*8+g)*4096);
    #pragma unroll
    for (int py=0;py<4;++py) for (int px=0;px<4;++px)
        op[(h0+by+py)*64 + (w0+bx+px)] = acc[py][px] + bv;
}

// ---------------- launch ----------------
extern "C" void kernel_launch(void* const* d_in, const int* in_sizes, int n_in,
                              void* d_out, int out_size, void* d_ws, size_t ws_size,
                              hipStream_t stream) {
    const float* x    = (const float*)d_in[0];
    const float* wrel = (const float*)d_in[1];
    const float* bias = (const float*)d_in[2];
    float* out        = (float*)d_out;

    if (ws_size >= (size_t)WS_NEEDED) {
        short* xb   = (short*)d_ws;
        short* bank = (short*)((char*)d_ws + XB_BYTES);
        zero_border<<<1040, 256, 0, stream>>>(xb);
        {
            dim3 g(64, 8, 16);
            prep_x2<<<g, 256, 0, stream>>>(x, xb);
        }
        prep_w<<<1152, 256, 0, stream>>>(wrel, bank);
        dim3 grid(16, 8, 16);
        gconv_mfma<<<grid, 256, 0, stream>>>(xb, bank, bias, out);
    } else {
        dim3 grid(16, 32, 16);
        gconv_direct<<<grid, 256, 0, stream>>>(x, wrel, bias, out);
    }
}

// Round 13
// 336.266 us; speedup vs baseline: 1.0344x; 1.0344x over previous
//
#include <hip/hip_runtime.h>
#include <stdint.h>

typedef short  bf16x8 __attribute__((ext_vector_type(8)));
typedef float  f32x4  __attribute__((ext_vector_type(4)));

// ---------------- common helpers ----------------

__device__ __forceinline__ short f2bf(float f) {
    uint32_t u = __builtin_bit_cast(uint32_t, f);
    u += 0x7FFFu + ((u >> 16) & 1u);          // RNE to bf16
    return (short)(u >> 16);
}

// u[g][s] = COMP[INV[g]][s] for p4m (verified by rounds 1-12 passing)
__device__ __forceinline__ int u_index(int g, int s) {
    int r  = g & 3, m  = g >> 2;
    int r2 = s & 3, ms = s >> 2;
    if (!m) { int rr = (r2 - r) & 3; return ms ? (4 + rr) : rr; }
    else    { int rr = (r - r2) & 3; return ms ? rr : (4 + rr); }
}

// async global->LDS, 16B per lane (LDS dest wave-uniform, HW adds lane*16)
__device__ __forceinline__ void gload_lds16(const void* g, void* l) {
    __builtin_amdgcn_global_load_lds(
        (const __attribute__((address_space(1))) uint32_t*)g,
        (__attribute__((address_space(3))) uint32_t*)l, 16, 0, 0);
}

// ---------------- workspace layout ----------------
// xb  : bf16 [16][66][66][512]            zero-padded NHWC input
// bank: bf16 [kc 16][kj 3][ki 3][kg 4][oc 512][8]  transformed weights;
//       per-(kc,kj) slab contiguous -> coalesced kj-granular staging
#define XB_BYTES  (16LL * 66 * 66 * 512 * 2)
#define BK_BYTES  (16LL * 9 * 4 * 512 * 8 * 2)
#define WS_NEEDED (XB_BYTES + BK_BYTES)

// ---------------- prep kernels ----------------

// Coalesced NCHW fp32 -> padded NHWC bf16, via LDS transpose.
__global__ __launch_bounds__(256) void prep_x2(const float* __restrict__ x,
                                               short* __restrict__ xb) {
    __shared__ float t[64][65];
    const int h = blockIdx.x, kc8 = blockIdx.y, b = blockIdx.z;
    const int k0 = kc8 * 64;
    const int tid = threadIdx.x;
    const int w  = tid & 63, kq = tid >> 6;
    const float* xp = x + ((size_t)(b * 512 + k0 + kq) * 4096) + h * 64 + w;
    #pragma unroll
    for (int i = 0; i < 16; ++i)
        t[kq + 4 * i][w] = xp[(size_t)(4 * i) * 4096];
    __syncthreads();
    const int w2 = tid >> 3, kk = tid & 7;
    #pragma unroll
    for (int half = 0; half < 2; ++half) {
        const int ww = w2 + 32 * half;
        bf16x8 v;
        #pragma unroll
        for (int j = 0; j < 8; ++j) v[j] = f2bf(t[kk * 8 + j][ww]);
        size_t o = (((size_t)b * 66 + h + 1) * 66 + (ww + 1)) * 512 + k0 + kk * 8;
        *reinterpret_cast<bf16x8*>(&xb[o]) = v;
    }
}

// zero the 1-px border of the padded NHWC buffer
__global__ __launch_bounds__(256) void zero_border(short* __restrict__ xb) {
    int idx = blockIdx.x * 256 + threadIdx.x;      // 16*260*64 = 266240
    if (idx >= 16 * 260 * 64) return;
    int kg = idx & 63;
    int rest = idx >> 6;
    int b  = rest / 260;
    int pe = rest - b * 260;
    int hh, ww;
    if      (pe < 66)  { hh = 0;            ww = pe; }
    else if (pe < 132) { hh = 65;           ww = pe - 66; }
    else if (pe < 196) { hh = pe - 132 + 1; ww = 0; }
    else               { hh = pe - 196 + 1; ww = 65; }
    size_t o = (((size_t)b * 66 + hh) * 66 + ww) * 512 + kg * 8;
    bf16x8 z = {0,0,0,0,0,0,0,0};
    *reinterpret_cast<bf16x8*>(&xb[o]) = z;
}

// wrel fp32 [64][64][8][3][3] -> bank bf16 [kc][kj][ki][kg][oc][8]
__global__ __launch_bounds__(256) void prep_w(const float* __restrict__ wrel,
                                              short* __restrict__ bank) {
    int tg = blockIdx.x * 256 + threadIdx.x;    // 9*16*4*512 = 294912
    int oc = tg & 511;
    int kg = (tg >> 9) & 3;
    int kc = (tg >> 11) & 15;
    int t  = tg >> 15;                          // 0..8
    int ki = t / 3, kj = t - ki * 3;
    int g = oc & 7, co = oc >> 3;
    int r = g & 3, m = g >> 2;
    int a0, b0;
    switch (r) {
        case 0:  a0 = ki;     b0 = kj;     break;
        case 1:  a0 = kj;     b0 = 2 - ki; break;
        case 2:  a0 = 2 - ki; b0 = 2 - kj; break;
        default: a0 = 2 - kj; b0 = ki;     break;
    }
    if (m) b0 = 2 - b0;
    int ci = kc * 4 + kg;
    const float* wp = wrel + (size_t)(co * 64 + ci) * 72 + a0 * 3 + b0;
    bf16x8 v;
    #pragma unroll
    for (int j = 0; j < 8; ++j) v[j] = f2bf(wp[u_index(g, j) * 9]);
    size_t o = (((((size_t)kc * 3 + kj) * 3 + ki) * 4 + kg) * 512 + oc) * 8;
    *reinterpret_cast<bf16x8*>(&bank[o]) = v;
}

// ---------------- main MFMA kernel ----------------
// block: 256 threads = 4 waves, 64 oc x 256 px (16x16 tile); wave 64oc x 64px.
// LDS 45KB -> 3 blocks/CU (12 waves, 3/SIMD): cross-block TLP covers stalls.
// X single-buffered (staged in a dedicated drain phase once per chunk);
// W kj-slabs ping-pong (staged overlapping compute), as in round 10.
#define XS_SH (21 * 512)            // 21 slots: 4kg x 336px, 16B frags
#define WB_SH (12 * 512)            // 12 slots: 3ki x 4kg x 64oc

#define STAGE_X(XS, kc)                                                    \
    {                                                                      \
        _Pragma("unroll")                                                  \
        for (int q = 0; q < 6; ++q) {                                      \
            int it = wid + 4 * q;                                          \
            if (it < 21)                                                   \
                gload_lds16(xb + (size_t)xoff[q] + (kc) * 32,              \
                            &XS[it * 512]);                                \
        }                                                                  \
    }

// one (kc,kj) weight slab: 3ki x 4kg x 64oc fragments, 3 loads/thread
#define STAGE_W(WB, kc, kj)                                                \
    {                                                                      \
        _Pragma("unroll")                                                  \
        for (int q = 0; q < 3; ++q) {                                      \
            int it = wid + 4 * q;                                          \
            gload_lds16(bank + (size_t)((kc) * 3 + (kj)) * 49152           \
                             + woff[q],                                    \
                        &WB[it * 512]);                                    \
        }                                                                  \
    }

// per kj-phase per wave: 6 B-reads + 3 ki x (4 A-reads, 16 MFMA)
#define COMPUTE_KJ(XS, WB, kj)                                             \
    {                                                                      \
        bf16x8 bfr[6];                                                     \
        _Pragma("unroll")                                                  \
        for (int rr = 0; rr < 6; ++rr)                                     \
            bfr[rr] = *reinterpret_cast<const bf16x8*>(                    \
                &XS[(lkg * 336 + (wid * 4 + rr) * 18 + l15 + (kj)) * 8]);  \
        _Pragma("unroll")                                                  \
        for (int ki = 0; ki < 3; ++ki) {                                   \
            bf16x8 a[4];                                                   \
            _Pragma("unroll")                                              \
            for (int mi = 0; mi < 4; ++mi)                                 \
                a[mi] = *reinterpret_cast<const bf16x8*>(                  \
                    &WB[((ki * 4 + lkg) * 64 + mi * 16 + l15) * 8]);       \
            _Pragma("unroll")                                              \
            for (int nj = 0; nj < 4; ++nj) {                               \
                bf16x8 bv = bfr[nj + ki];                                  \
                _Pragma("unroll")                                          \
                for (int mi = 0; mi < 4; ++mi)                             \
                    acc[mi][nj] = __builtin_amdgcn_mfma_f32_16x16x32_bf16( \
                        a[mi], bv, acc[mi][nj], 0, 0, 0);                  \
            }                                                              \
        }                                                                  \
    }

// One chunk. Entry: xs = X(kc), WA = W(kc,0), all visible.
// P0: stage W(kc,1)->WB    | compute kj0 from WA   | barrier
// P1: stage W(kc,2)->WA    | compute kj1 from WB   | barrier
// P2: stage W(kc+1,0)->WB  | compute kj2 from WA   | barrier
// P3: stage X(kc+1)->xs (drain phase)              | barrier
// Exit: WB holds W(kc+1,0) -> next chunk swaps (WA,WB).
#define CHUNK(kc, WA, WB)                                                  \
    {                                                                      \
        const int kcn = ((kc) < 15) ? (kc) + 1 : 15;                       \
        STAGE_W(WB, kc, 1);                                                \
        COMPUTE_KJ(xs, WA, 0);                                             \
        __syncthreads();                                                   \
        STAGE_W(WA, kc, 2);                                                \
        COMPUTE_KJ(xs, WB, 1);                                             \
        __syncthreads();                                                   \
        STAGE_W(WB, kcn, 0);                                               \
        COMPUTE_KJ(xs, WA, 2);                                             \
        __syncthreads();                                                   \
        STAGE_X(xs, kcn);                                                  \
        __syncthreads();                                                   \
    }

__global__ __launch_bounds__(256, 3) void gconv_mfma(
    const short* __restrict__ xb, const short* __restrict__ bank,
    const float* __restrict__ bias, float* __restrict__ out)
{
    __shared__ __attribute__((aligned(16))) short xs[XS_SH];
    __shared__ __attribute__((aligned(16))) short wbA[WB_SH], wbB[WB_SH];

    const int st  = blockIdx.x;           // 16 spatial tiles (4h x 4w)
    const int ot  = blockIdx.y;           // 8 oc tiles (64 oc each)
    const int b   = blockIdx.z;           // 16 batches
    const int h0  = (st >> 2) * 16;
    const int w0  = (st & 3) * 16;
    const int oc0 = ot * 64;

    const int tid  = threadIdx.x;
    const int lane = tid & 63;
    const int wid  = tid >> 6;            // 0..3 (row quad)
    const int l15  = lane & 15;
    const int lkg  = lane >> 4;

    f32x4 acc[4][4];
    #pragma unroll
    for (int i = 0; i < 4; ++i)
        #pragma unroll
        for (int j = 0; j < 4; ++j)
            #pragma unroll
            for (int e = 0; e < 4; ++e) acc[i][j][e] = 0.f;

    const int xrow_base = (b * 66 + h0) * 66 + w0;   // padded coords

    // per-thread global element offsets (32-bit ok: xb < 36M elems)
    int xoff[6];
    #pragma unroll
    for (int q = 0; q < 6; ++q) {
        int it = wid + 4 * q;
        if (it > 20) it = 20;                        // unused slot, safe addr
        int slot = it * 64 + lane;                   // < 1344
        int kg = slot / 336;                         // 0..3
        int px = slot - kg * 336;
        px = px < 324 ? px : 323;                    // pad slots -> dup
        int r = px / 18;
        int c = px - r * 18;
        xoff[q] = (xrow_base + r * 66 + c) * 512 + kg * 8;
    }
    int woff[3];
    #pragma unroll
    for (int q = 0; q < 3; ++q) {
        int it = wid + 4 * q;                        // 0..11 = (ki*4+kg)
        woff[q] = (it * 512 + oc0 + lane) * 8;
    }

    // ---- prologue ----
    STAGE_X(xs, 0);
    STAGE_W(wbA, 0, 0);
    __syncthreads();

    // ---- K-loop: 16 chunks x (3 kj-phases + 1 X-drain phase) ----
    for (int kc2 = 0; kc2 < 8; ++kc2) {
        CHUNK(2 * kc2,     wbA, wbB);
        CHUNK(2 * kc2 + 1, wbB, wbA);
    }

    // ---- epilogue: D row=(lane>>4)*4+reg -> oc, col=lane&15 -> pixel ----
    #pragma unroll
    for (int mi = 0; mi < 4; ++mi) {
        #pragma unroll
        for (int j = 0; j < 4; ++j) {
            const int oc_g = oc0 + mi * 16 + lkg * 4 + j;
            const float bv = bias[oc_g >> 3];
            float* op = out + ((size_t)b * 512 + oc_g) * 4096;
            #pragma unroll
            for (int nj = 0; nj < 4; ++nj) {
                const int hh = h0 + wid * 4 + nj;
                op[hh * 64 + w0 + l15] = acc[mi][nj][j] + bv;
            }
        }
    }
}

// ---------------- fp32 fallback (ws too small; verified round 1) ----------
__global__ __launch_bounds__(256) void gconv_direct(
    const float* __restrict__ x, const float* __restrict__ wrel,
    const float* __restrict__ bias, float* __restrict__ out)
{
    __shared__ float xsf[18][20];
    __shared__ float wsf[16][9];
    const int st = blockIdx.x, ct = blockIdx.y, b = blockIdx.z;
    const int h0 = (st >> 2) * 16, w0 = (st & 3) * 16, oc0 = ct * 16;
    const int tid = threadIdx.x;
    const int ch = tid & 15, blk = tid >> 4;
    const int by = (blk >> 2) * 4, bx = (blk & 3) * 4;
    const int oc = oc0 + ch, g = oc & 7, co = oc >> 3;
    const int wl_c = tid / 9, wl_k = tid - wl_c * 9;
    const int wl_i = wl_k / 3, wl_j = wl_k - wl_i * 3;
    const int wl_oc = oc0 + wl_c, wl_g = wl_oc & 7, wl_co = wl_oc >> 3;
    int a0, b0;
    { const int r = wl_g & 3, m = wl_g >> 2;
      switch (r) { case 0: a0=wl_i; b0=wl_j; break; case 1: a0=wl_j; b0=2-wl_i; break;
                   case 2: a0=2-wl_i; b0=2-wl_j; break; default: a0=2-wl_j; b0=wl_i; break; }
      if (m) b0 = 2 - b0; }
    float acc[4][4];
    #pragma unroll
    for (int i=0;i<4;++i) for (int j=0;j<4;++j) acc[i][j]=0.f;
    for (int t = 0; t < 512; ++t) {
        const int ci = t >> 3, s = t & 7;
        __syncthreads();
        const float* xp = x + (((size_t)(b * 64 + ci) * 8 + s) * 4096);
        for (int idx = tid; idx < 18 * 18; idx += 256) {
            const int rr = idx / 18, cc = idx - rr * 18;
            const int gh = h0 - 1 + rr, gw = w0 - 1 + cc;
            float v = 0.f;
            if (gh >= 0 && gh < 64 && gw >= 0 && gw < 64) v = xp[gh * 64 + gw];
            xsf[rr][cc] = v;
        }
        if (tid < 144) {
            const int u = u_index(wl_g, s);
            wsf[wl_c][wl_k] = wrel[((size_t)(wl_co*64+ci)*8+u)*9 + a0*3 + b0];
        }
        __syncthreads();
        float wr[9];
        #pragma unroll
        for (int k=0;k<9;++k) wr[k]=wsf[ch][k];
        float xv[6][6];
        #pragma unroll
        for (int i=0;i<6;++i) for (int j=0;j<6;++j) xv[i][j]=xsf[by+i][bx+j];
        #pragma unroll
        for (int py=0;py<4;++py) for (int px=0;px<4;++px)
            for (int ki=0;ki<3;++ki) for (int kj=0;kj<3;++kj)
                acc[py][px] += xv[py+ki][px+kj]*wr[ki*3+kj];
    }
    const float bv = bias[co];
    float* op = out + (((size_t)(b*64+co)*8+g)*4096);
    #pragma unroll
    for (int py=0;py<4;++py) for (int px=0;px<4;++px)
        op[(h0+by+py)*64 + (w0+bx+px)] = acc[py][px] + bv;
}

// ---------------- launch ----------------
extern "C" void kernel_launch(void* const* d_in, const int* in_sizes, int n_in,
                              void* d_out, int out_size, void* d_ws, size_t ws_size,
                              hipStream_t stream) {
    const float* x    = (const float*)d_in[0];
    const float* wrel = (const float*)d_in[1];
    const float* bias = (const float*)d_in[2];
    float* out        = (float*)d_out;

    if (ws_size >= (size_t)WS_NEEDED) {
        short* xb   = (short*)d_ws;
        short* bank = (short*)((char*)d_ws + XB_BYTES);
        zero_border<<<1040, 256, 0, stream>>>(xb);
        {
            dim3 g(64, 8, 16);
            prep_x2<<<g, 256, 0, stream>>>(x, xb);
        }
        prep_w<<<1152, 256, 0, stream>>>(wrel, bank);
        dim3 grid(16, 8, 16);
        gconv_mfma<<<grid, 256, 0, stream>>>(xb, bank, bias, out);
    } else {
        dim3 grid(16, 32, 16);
        gconv_direct<<<grid, 256, 0, stream>>>(x, wrel, bias, out);
    }
}

// Round 14
// 294.232 us; speedup vs baseline: 1.1821x; 1.1429x over previous
//
#include <hip/hip_runtime.h>
#include <stdint.h>

typedef short  bf16x8 __attribute__((ext_vector_type(8)));
typedef float  f32x4  __attribute__((ext_vector_type(4)));

// ---------------- common helpers ----------------

__device__ __forceinline__ short f2bf(float f) {
    uint32_t u = __builtin_bit_cast(uint32_t, f);
    u += 0x7FFFu + ((u >> 16) & 1u);          // RNE to bf16
    return (short)(u >> 16);
}

// u[g][s] = COMP[INV[g]][s] for p4m (verified by rounds 1-13 passing)
__device__ __forceinline__ int u_index(int g, int s) {
    int r  = g & 3, m  = g >> 2;
    int r2 = s & 3, ms = s >> 2;
    if (!m) { int rr = (r2 - r) & 3; return ms ? (4 + rr) : rr; }
    else    { int rr = (r - r2) & 3; return ms ? rr : (4 + rr); }
}

// async global->LDS, 16B per lane (LDS dest wave-uniform, HW adds lane*16)
__device__ __forceinline__ void gload_lds16(const void* g, void* l) {
    __builtin_amdgcn_global_load_lds(
        (const __attribute__((address_space(1))) uint32_t*)g,
        (__attribute__((address_space(3))) uint32_t*)l, 16, 0, 0);
}

// ---------------- workspace layout ----------------
// xb  : bf16 [16][66][66][512]            zero-padded NHWC input
// bank: bf16 [kc 16][kj 3][ki 3][kg 4][oc 512][8]  transformed weights;
//       per-(kc,kj) slab contiguous -> coalesced kj-granular staging
#define XB_BYTES  (16LL * 66 * 66 * 512 * 2)
#define BK_BYTES  (16LL * 9 * 4 * 512 * 8 * 2)
#define WS_NEEDED (XB_BYTES + BK_BYTES)

// ---------------- prep kernels ----------------

// Coalesced NCHW fp32 -> padded NHWC bf16, via LDS transpose.
__global__ __launch_bounds__(256) void prep_x2(const float* __restrict__ x,
                                               short* __restrict__ xb) {
    __shared__ float t[64][65];
    const int h = blockIdx.x, kc8 = blockIdx.y, b = blockIdx.z;
    const int k0 = kc8 * 64;
    const int tid = threadIdx.x;
    const int w  = tid & 63, kq = tid >> 6;
    const float* xp = x + ((size_t)(b * 512 + k0 + kq) * 4096) + h * 64 + w;
    #pragma unroll
    for (int i = 0; i < 16; ++i)
        t[kq + 4 * i][w] = xp[(size_t)(4 * i) * 4096];
    __syncthreads();
    const int w2 = tid >> 3, kk = tid & 7;
    #pragma unroll
    for (int half = 0; half < 2; ++half) {
        const int ww = w2 + 32 * half;
        bf16x8 v;
        #pragma unroll
        for (int j = 0; j < 8; ++j) v[j] = f2bf(t[kk * 8 + j][ww]);
        size_t o = (((size_t)b * 66 + h + 1) * 66 + (ww + 1)) * 512 + k0 + kk * 8;
        *reinterpret_cast<bf16x8*>(&xb[o]) = v;
    }
}

// zero the 1-px border of the padded NHWC buffer
__global__ __launch_bounds__(256) void zero_border(short* __restrict__ xb) {
    int idx = blockIdx.x * 256 + threadIdx.x;      // 16*260*64 = 266240
    if (idx >= 16 * 260 * 64) return;
    int kg = idx & 63;
    int rest = idx >> 6;
    int b  = rest / 260;
    int pe = rest - b * 260;
    int hh, ww;
    if      (pe < 66)  { hh = 0;            ww = pe; }
    else if (pe < 132) { hh = 65;           ww = pe - 66; }
    else if (pe < 196) { hh = pe - 132 + 1; ww = 0; }
    else               { hh = pe - 196 + 1; ww = 65; }
    size_t o = (((size_t)b * 66 + hh) * 66 + ww) * 512 + kg * 8;
    bf16x8 z = {0,0,0,0,0,0,0,0};
    *reinterpret_cast<bf16x8*>(&xb[o]) = z;
}

// wrel fp32 [64][64][8][3][3] -> bank bf16 [kc][kj][ki][kg][oc][8]
__global__ __launch_bounds__(256) void prep_w(const float* __restrict__ wrel,
                                              short* __restrict__ bank) {
    int tg = blockIdx.x * 256 + threadIdx.x;    // 9*16*4*512 = 294912
    int oc = tg & 511;
    int kg = (tg >> 9) & 3;
    int kc = (tg >> 11) & 15;
    int t  = tg >> 15;                          // 0..8
    int ki = t / 3, kj = t - ki * 3;
    int g = oc & 7, co = oc >> 3;
    int r = g & 3, m = g >> 2;
    int a0, b0;
    switch (r) {
        case 0:  a0 = ki;     b0 = kj;     break;
        case 1:  a0 = kj;     b0 = 2 - ki; break;
        case 2:  a0 = 2 - ki; b0 = 2 - kj; break;
        default: a0 = 2 - kj; b0 = ki;     break;
    }
    if (m) b0 = 2 - b0;
    int ci = kc * 4 + kg;
    const float* wp = wrel + (size_t)(co * 64 + ci) * 72 + a0 * 3 + b0;
    bf16x8 v;
    #pragma unroll
    for (int j = 0; j < 8; ++j) v[j] = f2bf(wp[u_index(g, j) * 9]);
    size_t o = (((((size_t)kc * 3 + kj) * 3 + ki) * 4 + kg) * 512 + oc) * 8;
    *reinterpret_cast<bf16x8*>(&bank[o]) = v;
}

// ---------------- main MFMA kernel ----------------
// block: 256 threads = 4 waves, 64 oc x 256 px (16x16 tile); wave 64oc x 64px.
// REGISTER DOUBLE-BUFFER: each phase's MFMAs consume fragments prefetched
// during the PREVIOUS phase, so ds_reads(p+1) overlap MFMAs(p).
// W: 3 rotating kj-slab LDS buffers (slab kj -> buf kj; staged 2 phases
// ahead of read). X: LDS dbuf (staged P0, first read P2).
// LDS 78KB -> 2 blocks/CU; VGPR ~235 (acc 64 + 2x72 frag sets).
#define XS_SH (21 * 512)            // 21 slots: 4kg x 336px, 16B frags
#define WB_SH (12 * 512)            // 12 slots: 3ki x 4kg x 64oc

struct FragSet { bf16x8 b[6]; bf16x8 a[3][4]; };

#define STAGE_X(XS, kc)                                                    \
    {                                                                      \
        _Pragma("unroll")                                                  \
        for (int q = 0; q < 6; ++q) {                                      \
            int it = wid + 4 * q;                                          \
            if (it < 21)                                                   \
                gload_lds16(xb + (size_t)xoff[q] + (kc) * 32,              \
                            &XS[it * 512]);                                \
        }                                                                  \
    }

// one (kc,kj) weight slab: 3ki x 4kg x 64oc fragments, 3 loads/thread
#define STAGE_W(WB, kc, kj)                                                \
    {                                                                      \
        _Pragma("unroll")                                                  \
        for (int q = 0; q < 3; ++q) {                                      \
            int it = wid + 4 * q;                                          \
            gload_lds16(bank + (size_t)((kc) * 3 + (kj)) * 49152           \
                             + woff[q],                                    \
                        &WB[it * 512]);                                    \
        }                                                                  \
    }

// load one phase's fragments (6 B + 12 A) into registers
#define PREFETCH(R, XS, WB, kj)                                            \
    {                                                                      \
        _Pragma("unroll")                                                  \
        for (int rr = 0; rr < 6; ++rr)                                     \
            R.b[rr] = *reinterpret_cast<const bf16x8*>(                    \
                &XS[(lkg * 336 + (wid * 4 + rr) * 18 + l15 + (kj)) * 8]);  \
        _Pragma("unroll")                                                  \
        for (int ki = 0; ki < 3; ++ki)                                     \
            _Pragma("unroll")                                              \
            for (int mi = 0; mi < 4; ++mi)                                 \
                R.a[ki][mi] = *reinterpret_cast<const bf16x8*>(            \
                    &WB[((ki * 4 + lkg) * 64 + mi * 16 + l15) * 8]);       \
    }

// 48 MFMAs from registers only (no LDS dependency)
#define MFMA_BURST(R)                                                      \
    {                                                                      \
        _Pragma("unroll")                                                  \
        for (int ki = 0; ki < 3; ++ki)                                     \
            _Pragma("unroll")                                              \
            for (int nj = 0; nj < 4; ++nj) {                               \
                bf16x8 bv = R.b[nj + ki];                                  \
                _Pragma("unroll")                                          \
                for (int mi = 0; mi < 4; ++mi)                             \
                    acc[mi][nj] = __builtin_amdgcn_mfma_f32_16x16x32_bf16( \
                        R.a[ki][mi], bv, acc[mi][nj], 0, 0, 0);            \
            }                                                              \
    }

// One chunk. Entry: XC=X(kc) visible; wb0=W(kc,0), wb1=W(kc,1) visible;
// RA holds fragments for (kc, kj0).
// P0: stage W(kc,2)->wb2, X(kc+1)->XN | prefetch RB<-(XC,wb1,kj1) | MFMA(RA)
// P1: stage W(kc+1,0)->wb0           | prefetch RA<-(XC,wb2,kj2) | MFMA(RB)
// P2: stage W(kc+1,1)->wb1           | prefetch RB<-(XN,wb0,kj0) | MFMA(RA)
// Exit: RB holds (kc+1, kj0) -> next chunk swaps (RA,RB) and (XC,XN).
#define CHUNK(kc, XC, XN, RA, RB)                                          \
    {                                                                      \
        const int kcn = ((kc) < 15) ? (kc) + 1 : 15;                       \
        STAGE_W(wb2, kc, 2);                                               \
        STAGE_X(XN, kcn);                                                  \
        PREFETCH(RB, XC, wb1, 1);                                          \
        MFMA_BURST(RA);                                                    \
        __syncthreads();                                                   \
        STAGE_W(wb0, kcn, 0);                                              \
        PREFETCH(RA, XC, wb2, 2);                                          \
        MFMA_BURST(RB);                                                    \
        __syncthreads();                                                   \
        STAGE_W(wb1, kcn, 1);                                              \
        PREFETCH(RB, XN, wb0, 0);                                          \
        MFMA_BURST(RA);                                                    \
        __syncthreads();                                                   \
    }

__global__ __launch_bounds__(256, 2) void gconv_mfma(
    const short* __restrict__ xb, const short* __restrict__ bank,
    const float* __restrict__ bias, float* __restrict__ out)
{
    __shared__ __attribute__((aligned(16))) short xsA[XS_SH], xsB[XS_SH];
    __shared__ __attribute__((aligned(16))) short wb0[WB_SH], wb1[WB_SH],
                                                  wb2[WB_SH];

    const int st  = blockIdx.x;           // 16 spatial tiles (4h x 4w)
    const int ot  = blockIdx.y;           // 8 oc tiles (64 oc each)
    const int b   = blockIdx.z;           // 16 batches
    const int h0  = (st >> 2) * 16;
    const int w0  = (st & 3) * 16;
    const int oc0 = ot * 64;

    const int tid  = threadIdx.x;
    const int lane = tid & 63;
    const int wid  = tid >> 6;            // 0..3 (row quad)
    const int l15  = lane & 15;
    const int lkg  = lane >> 4;

    f32x4 acc[4][4];
    #pragma unroll
    for (int i = 0; i < 4; ++i)
        #pragma unroll
        for (int j = 0; j < 4; ++j)
            #pragma unroll
            for (int e = 0; e < 4; ++e) acc[i][j][e] = 0.f;

    const int xrow_base = (b * 66 + h0) * 66 + w0;   // padded coords

    // per-thread global element offsets (32-bit ok: xb < 36M elems)
    int xoff[6];
    #pragma unroll
    for (int q = 0; q < 6; ++q) {
        int it = wid + 4 * q;
        if (it > 20) it = 20;                        // unused slot, safe addr
        int slot = it * 64 + lane;                   // < 1344
        int kg = slot / 336;                         // 0..3
        int px = slot - kg * 336;
        px = px < 324 ? px : 323;                    // pad slots -> dup
        int r = px / 18;
        int c = px - r * 18;
        xoff[q] = (xrow_base + r * 66 + c) * 512 + kg * 8;
    }
    int woff[3];
    #pragma unroll
    for (int q = 0; q < 3; ++q) {
        int it = wid + 4 * q;                        // 0..11 = (ki*4+kg)
        woff[q] = (it * 512 + oc0 + lane) * 8;
    }

    FragSet fsA, fsB;

    // ---- prologue: X(0), W(0,0), W(0,1); then prefetch (0,kj0) ----
    STAGE_X(xsA, 0);
    STAGE_W(wb0, 0, 0);
    STAGE_W(wb1, 0, 1);
    __syncthreads();
    PREFETCH(fsA, xsA, wb0, 0);

    // ---- K-loop: 16 chunks x 3 kj-phases, register-pipelined ----
    for (int kc2 = 0; kc2 < 8; ++kc2) {
        CHUNK(2 * kc2,     xsA, xsB, fsA, fsB);
        CHUNK(2 * kc2 + 1, xsB, xsA, fsB, fsA);
    }

    // ---- epilogue: D row=(lane>>4)*4+reg -> oc, col=lane&15 -> pixel ----
    #pragma unroll
    for (int mi = 0; mi < 4; ++mi) {
        #pragma unroll
        for (int j = 0; j < 4; ++j) {
            const int oc_g = oc0 + mi * 16 + lkg * 4 + j;
            const float bv = bias[oc_g >> 3];
            float* op = out + ((size_t)b * 512 + oc_g) * 4096;
            #pragma unroll
            for (int nj = 0; nj < 4; ++nj) {
                const int hh = h0 + wid * 4 + nj;
                op[hh * 64 + w0 + l15] = acc[mi][nj][j] + bv;
            }
        }
    }
}

// ---------------- fp32 fallback (ws too small; verified round 1) ----------
__global__ __launch_bounds__(256) void gconv_direct(
    const float* __restrict__ x, const float* __restrict__ wrel,
    const float* __restrict__ bias, float* __restrict__ out)
{
    __shared__ float xsf[18][20];
    __shared__ float wsf[16][9];
    const int st = blockIdx.x, ct = blockIdx.y, b = blockIdx.z;
    const int h0 = (st >> 2) * 16, w0 = (st & 3) * 16, oc0 = ct * 16;
    const int tid = threadIdx.x;
    const int ch = tid & 15, blk = tid >> 4;
    const int by = (blk >> 2) * 4, bx = (blk & 3) * 4;
    const int oc = oc0 + ch, g = oc & 7, co = oc >> 3;
    const int wl_c = tid / 9, wl_k = tid - wl_c * 9;
    const int wl_i = wl_k / 3, wl_j = wl_k - wl_i * 3;
    const int wl_oc = oc0 + wl_c, wl_g = wl_oc & 7, wl_co = wl_oc >> 3;
    int a0, b0;
    { const int r = wl_g & 3, m = wl_g >> 2;
      switch (r) { case 0: a0=wl_i; b0=wl_j; break; case 1: a0=wl_j; b0=2-wl_i; break;
                   case 2: a0=2-wl_i; b0=2-wl_j; break; default: a0=2-wl_j; b0=wl_i; break; }
      if (m) b0 = 2 - b0; }
    float acc[4][4];
    #pragma unroll
    for (int i=0;i<4;++i) for (int j=0;j<4;++j) acc[i][j]=0.f;
    for (int t = 0; t < 512; ++t) {
        const int ci = t >> 3, s = t & 7;
        __syncthreads();
        const float* xp = x + (((size_t)(b * 64 + ci) * 8 + s) * 4096);
        for (int idx = tid; idx < 18 * 18; idx += 256) {
            const int rr = idx / 18, cc = idx - rr * 18;
            const int gh = h0 - 1 + rr, gw = w0 - 1 + cc;
            float v = 0.f;
            if (gh >= 0 && gh < 64 && gw >= 0 && gw < 64) v = xp[gh * 64 + gw];
            xsf[rr][cc] = v;
        }
        if (tid < 144) {
            const int u = u_index(wl_g, s);
            wsf[wl_c][wl_k] = wrel[((size_t)(wl_co*64+ci)*8+u)*9 + a0*3 + b0];
        }
        __syncthreads();
        float wr[9];
        #pragma unroll
        for (int k=0;k<9;++k) wr[k]=wsf[ch][k];
        float xv[6][6];
        #pragma unroll
        for (int i=0;i<6;++i) for (int j=0;j<6;++j) xv[i][j]=xsf[by+i][bx+j];
        #pragma unroll
        for (int py=0;py<4;++py) for (int px=0;px<4;++px)
            for (int ki=0;ki<3;++ki) for (int kj=0;kj<3;++kj)
                acc[py][px] += xv[py+ki][px+kj]*wr[ki*3+kj];
    }
    const float bv = bias[co];
    float* op = out + (((size_t)(b*64+co)*8+g)*4096);
    #pragma unroll
    for (int py=0;py<4;++py) for (int px=0;px<4;++px)
        op[(h0+by+py)*64 + (w0+bx+px)] = acc[py][px] + bv;
}

// ---------------- launch ----------------
extern "C" void kernel_launch(void* const* d_in, const int* in_sizes, int n_in,
                              void* d_out, int out_size, void* d_ws, size_t ws_size,
                              hipStream_t stream) {
    const float* x    = (const float*)d_in[0];
    const float* wrel = (const float*)d_in[1];
    const float* bias = (const float*)d_in[2];
    float* out        = (float*)d_out;

    if (ws_size >= (size_t)WS_NEEDED) {
        short* xb   = (short*)d_ws;
        short* bank = (short*)((char*)d_ws + XB_BYTES);
        zero_border<<<1040, 256, 0, stream>>>(xb);
        {
            dim3 g(64, 8, 16);
            prep_x2<<<g, 256, 0, stream>>>(x, xb);
        }
        prep_w<<<1152, 256, 0, stream>>>(wrel, bank);
        dim3 grid(16, 8, 16);
        gconv_mfma<<<grid, 256, 0, stream>>>(xb, bank, bias, out);
    } else {
        dim3 grid(16, 32, 16);
        gconv_direct<<<grid, 256, 0, stream>>>(x, wrel, bias, out);
    }
}